// Round 4
// baseline (733.322 us; speedup 1.0000x reference)
//
#include <hip/hip_runtime.h>
#include <stdint.h>

// ---------------------------------------------------------------------------
// Binarized CNN (brevitas M5). Activations after bin_act are exactly +/-1,
// weights exactly +/-0.1  ->  layers 2/3/5 + FC are XNOR-popcount convs
// computed EXACTLY in integers. Only conv1 is a real fp32 conv.
// Stage 1 computed twice (stats pass, sign pass): no y1 materialization.
// R3 fix: conv1 weights pre-signed into w1p (SGPR-loadable, kills per-thread
// cmp/cndmask = half of VALU work), x taps hoisted to registers (kills
// per-cgi LDS re-reads). R2 rocprof: conv1 VALU-bound at 12% FMA peak.
// ---------------------------------------------------------------------------

constexpr int Bn  = 64;
constexpr int H1  = 3980;        // conv1 output rows
constexpr int J1  = 1990;        // after pool2x1
constexpr int H2o = 1991, J2 = 995;
constexpr int H3o = 994,  J3 = 497;
constexpr int H5o = 499,  J5 = 249;
constexpr int FCW = 249 * 8;     // u64 words per FC row (512*249 bits)

// ------------------------- weight prep -------------------------------------
// bit = 1  <=>  weight >= 0  <=>  +0.1      (activation bit = 1 <=> +1)
// Also: w1p[cg][kg][ch*4+jj] = sign(w1[cg*4+ch][kg*4+jj]) * 0.1  (fp32)
__global__ void binarize_all(const float* __restrict__ w2, const float* __restrict__ w3,
                             const float* __restrict__ w5, const float* __restrict__ wfc,
                             const float* __restrict__ w1,
                             uint64_t* __restrict__ wb2, uint64_t* __restrict__ wb3,
                             uint64_t* __restrict__ wb5, uint64_t* __restrict__ wbf,
                             float* __restrict__ w1p)
{
    int idx = blockIdx.x * 256 + threadIdx.x;
    if (idx < 1024) {                                  // w2: [128][128][4] -> [c][k][wdx]
        int wdx = idx & 1, k = (idx >> 1) & 3, c = idx >> 3;
        uint64_t v = 0;
        for (int ci = 0; ci < 64; ++ci)
            if (w2[((size_t)c * 128 + (wdx * 64 + ci)) * 4 + k] >= 0.f) v |= 1ull << ci;
        wb2[idx] = v;
    } else if (idx < 3072) {                           // w3: [256][128][4]
        int t = idx - 1024;
        int wdx = t & 1, k = (t >> 1) & 3, c = t >> 3;
        uint64_t v = 0;
        for (int ci = 0; ci < 64; ++ci)
            if (w3[((size_t)c * 128 + (wdx * 64 + ci)) * 4 + k] >= 0.f) v |= 1ull << ci;
        wb3[t] = v;
    } else if (idx < 9216) {                           // w5: [512][256][3]
        int t = idx - 3072;
        int wdx = t & 3, k = (t >> 2) % 3, c = t / 12;
        uint64_t v = 0;
        for (int ci = 0; ci < 64; ++ci)
            if (w5[((size_t)c * 256 + (wdx * 64 + ci)) * 3 + k] >= 0.f) v |= 1ull << ci;
        wb5[t] = v;
    } else if (idx < 9216 + 69720) {                   // wfc: [35][512*249] -> [oc][hh][wdx]
        int t = idx - 9216;
        int wdx = t & 7, hh = (t >> 3) % 249, oc = t / (249 * 8);
        uint64_t v = 0;
        for (int ci = 0; ci < 64; ++ci)
            if (wfc[(size_t)oc * 127488 + (size_t)(wdx * 64 + ci) * 249 + hh] >= 0.f)
                v |= 1ull << ci;
        wbf[t] = v;
    } else if (idx < 9216 + 69720 + 10752) {           // w1p: [32][21][16]
        int t  = idx - (9216 + 69720);
        int cg = t / 336, r = t % 336;
        int kg = r >> 4, e = r & 15;
        int ch = e >> 2, jj = e & 3;
        w1p[t] = (w1[(size_t)(cg * 4 + ch) * 84 + kg * 4 + jj] >= 0.f) ? 0.1f : -0.1f;
    }
}

// ------------------------------- stage 1 ------------------------------------
// Fused conv1 (stride 4, K=84) computed per row-pair j (rows 2j, 2j+1).
// sign_mode==0: per-channel (sum, sumsq) partials (deterministic wave slices).
// sign_mode==1: BN (exact ref rounding order) + sign + maxpool(2,1) + bitpack.
// blockIdx.z selects the channel half (word): cg in [16z, 16z+16).
__global__ __launch_bounds__(256) void conv1_fused(
    const float* __restrict__ x, const float* __restrict__ w1p,
    const float* __restrict__ b1, const float2* __restrict__ bnp,
    const float* __restrict__ g, const float* __restrict__ be,
    float* __restrict__ part, uint64_t* __restrict__ a1, const int sign_mode)
{
    __shared__ float4 xe[268], xo[268];     // x4 even/odd split: lane stride 16 B
    __shared__ float  statw[4][128];        // per-wave (sum,sumsq) slices
    const int n    = blockIdx.y;
    const int j0   = blockIdx.x << 8;       // 256 row-pairs per block
    const int z    = blockIdx.z;            // channel word (0/1)
    const int tid  = threadIdx.x;
    const int wave = tid >> 6, lane = tid & 63;

    if (!sign_mode)
        for (int i = tid; i < 512; i += 256) ((float*)statw)[i] = 0.f;

    const float4* x4 = (const float4*)x + (size_t)n * 4000;
    for (int i = tid; i < 532; i += 256) {
        int gi = 2 * j0 + i;
        float4 v = (gi < 4000) ? x4[gi] : make_float4(0.f, 0.f, 0.f, 0.f);
        if (i & 1) xo[i >> 1] = v; else xe[i >> 1] = v;
    }
    __syncthreads();

    const int  jl    = tid;
    const int  j     = j0 + jl;
    const bool valid = j < J1;

    // hoist all 22 x taps into registers: inner loop is pure FMA
    float4 xev[11], xov[11];
    #pragma unroll
    for (int t = 0; t < 11; ++t) { xev[t] = xe[jl + t]; xov[t] = xo[jl + t]; }

    uint64_t bits = 0;

    for (int cgi = 0; cgi < 16; ++cgi) {
        const int cg = z * 16 + cgi;
        float acc0[4] = {0.f, 0.f, 0.f, 0.f};
        float acc1[4] = {0.f, 0.f, 0.f, 0.f};
        const float4* wp = (const float4*)(w1p + cg * 336);   // [kg][ch] float4
        #pragma unroll
        for (int kg = 0; kg < 21; ++kg) {
            // block-uniform address -> s_load; weights live in SGPRs
            float sw[4][4];
            #pragma unroll
            for (int ch = 0; ch < 4; ++ch) {
                float4 wv = wp[kg * 4 + ch];
                sw[ch][0] = wv.x; sw[ch][1] = wv.y; sw[ch][2] = wv.z; sw[ch][3] = wv.w;
            }
            float4 xa, xb;                               // row 2j tap / row 2j+1 tap
            if (kg & 1) { xa = xov[(kg - 1) / 2]; xb = xev[(kg + 1) / 2]; }
            else        { xa = xev[kg / 2];       xb = xov[kg / 2]; }
            const float xav[4] = {xa.x, xa.y, xa.z, xa.w};
            const float xbv[4] = {xb.x, xb.y, xb.z, xb.w};
            #pragma unroll
            for (int jj = 0; jj < 4; ++jj)               // same chain order as R1
                #pragma unroll
                for (int ch = 0; ch < 4; ++ch) {
                    acc0[ch] = fmaf(sw[ch][jj], xav[jj], acc0[ch]);
                    acc1[ch] = fmaf(sw[ch][jj], xbv[jj], acc1[ch]);
                }
        }
        #pragma unroll
        for (int ch = 0; ch < 4; ++ch) {
            const int c = cg * 4 + ch;
            const float bv = b1[c];
            float v0 = acc0[ch] + bv;
            float v1 = acc1[ch] + bv;
            if (!valid) { v0 = 0.f; v1 = 0.f; }
            if (sign_mode) {
                const float2 mi = bnp[c];
                const float gg = g[c], bbe = be[c];
                float t0 = __fadd_rn(__fmul_rn(__fmul_rn(__fsub_rn(v0, mi.x), mi.y), gg), bbe);
                float t1 = __fadd_rn(__fmul_rn(__fmul_rn(__fsub_rn(v1, mi.x), mi.y), gg), bbe);
                if ((t0 >= 0.f) || (t1 >= 0.f)) bits |= 1ull << (c & 63);
            } else {
                float s = v0 + v1;
                float q = fmaf(v1, v1, fmaf(v0, v0, 0.f));
                #pragma unroll
                for (int o = 32; o > 0; o >>= 1) {
                    s += __shfl_xor(s, o, 64);
                    q += __shfl_xor(q, o, 64);
                }
                if (lane == 0) {
                    statw[wave][(cgi * 4 + ch) * 2 + 0] += s;
                    statw[wave][(cgi * 4 + ch) * 2 + 1] += q;
                }
            }
        }
    }

    if (sign_mode) {
        if (valid) a1[((size_t)n * J1 + j) * 2 + z] = bits;
    } else {
        __syncthreads();
        if (tid < 128) {
            float v = ((statw[0][tid] + statw[1][tid]) + statw[2][tid]) + statw[3][tid];
            part[((size_t)((n * 8 + blockIdx.x) * 2 + z)) * 128 + tid] = v;
        }
    }
}

// Parallel BN-stat reduce for stage 1: one block per channel (128 blocks).
__global__ __launch_bounds__(256) void bn_reduce1(const float* __restrict__ part,
                                                  float2* __restrict__ bnp)
{
    __shared__ double sS[256], sQ[256];
    const int c = blockIdx.x, t = threadIdx.x;
    const int z = c >> 6, cl = c & 63;
    double S = 0.0, SS = 0.0;
    for (int b = t; b < 512; b += 256) {
        const float2 p = *(const float2*)(part + ((size_t)(b * 2 + z)) * 128 + cl * 2);
        S += (double)p.x; SS += (double)p.y;
    }
    sS[t] = S; sQ[t] = SS;
    __syncthreads();
    for (int o = 128; o > 0; o >>= 1) {
        if (t < o) { sS[t] += sS[t + o]; sQ[t] += sQ[t + o]; }
        __syncthreads();
    }
    if (t == 0) {
        const double N = (double)Bn * H1;
        double mu  = sS[0] / N;
        double var = sQ[0] / N - mu * mu;
        bnp[c] = make_float2((float)mu, (float)(1.0 / sqrt(var + 1e-5)));
    }
}

// --------------------------- binary convs ----------------------------------
// q = 64*CINW*V - 2*popc(a xor w) over valid taps; y = 0.1*q + b (exact int q)
template<int CINW, int KK, int PAD, int COUT>
__global__ __launch_bounds__(COUT) void bconv(
    const uint64_t* __restrict__ ain, const uint64_t* __restrict__ wb,
    const int HIN, const int HOUT,
    int16_t* __restrict__ qout, int* __restrict__ part)
{
    __shared__ uint64_t rows[(64 + KK - 1) * CINW];
    const int n  = blockIdx.y;
    const int h0 = blockIdx.x << 6;
    const int c  = threadIdx.x;
    for (int i = c; i < (64 + KK - 1) * CINW; i += COUT) {
        int r = h0 - PAD + i / CINW;
        rows[i] = (r >= 0 && r < HIN) ? ain[((size_t)n * HIN + r) * CINW + (i % CINW)] : 0ull;
    }
    __syncthreads();
    uint64_t wreg[KK * CINW];
    #pragma unroll
    for (int i = 0; i < KK * CINW; ++i) wreg[i] = wb[(size_t)c * KK * CINW + i];
    int sq = 0, sq2 = 0;
    const int hmax = min(64, HOUT - h0);
    for (int i = 0; i < hmax; ++i) {
        const int h   = h0 + i;
        const int klo = max(0, PAD - h);
        const int khi = min(KK, HIN + PAD - h);
        int X = 0;
        if (klo == 0 && khi == KK) {
            #pragma unroll
            for (int k = 0; k < KK; ++k)
                #pragma unroll
                for (int wd = 0; wd < CINW; ++wd)
                    X += __popcll(rows[(i + k) * CINW + wd] ^ wreg[k * CINW + wd]);
        } else {
            for (int k = klo; k < khi; ++k)
                #pragma unroll
                for (int wd = 0; wd < CINW; ++wd)
                    X += __popcll(rows[(i + k) * CINW + wd] ^ wreg[k * CINW + wd]);
        }
        const int q = 64 * CINW * (khi - klo) - 2 * X;
        qout[((size_t)n * HOUT + h) * COUT + c] = (int16_t)q;
        sq += q; sq2 += q * q;
    }
    const size_t blk = (size_t)n * gridDim.x + blockIdx.x;
    part[(blk * COUT + c) * 2 + 0] = sq;
    part[(blk * COUT + c) * 2 + 1] = sq2;
}

// Parallel q-stat reduce: one block per channel; integer sums exact.
__global__ __launch_bounds__(256) void bn_reduce_q(
    const int* __restrict__ part, const int nblk, const int C,
    const double N, const float* __restrict__ bias, float2* __restrict__ bnp)
{
    __shared__ long long sS[256], sQ[256];
    const int c = blockIdx.x, t = threadIdx.x;
    long long Sq = 0, Sq2 = 0;
    for (int b = t; b < nblk; b += 256) {
        const int2 p = *(const int2*)(part + ((size_t)b * C + c) * 2);
        Sq += p.x; Sq2 += p.y;
    }
    sS[t] = Sq; sQ[t] = Sq2;
    __syncthreads();
    for (int o = 128; o > 0; o >>= 1) {
        if (t < o) { sS[t] += sS[t + o]; sQ[t] += sQ[t + o]; }
        __syncthreads();
    }
    if (t == 0) {
        const double bb = (double)bias[c];
        const double S  = 0.1 * (double)sS[0] + N * bb;              // sum(y), exact
        const double SS = 0.01 * (double)sQ[0] + 0.2 * bb * (double)sS[0] + N * bb * bb;
        const double mu = S / N;
        const double var = SS / N - mu * mu;
        bnp[c] = make_float2((float)mu, (float)(1.0 / sqrt(var + 1e-5)));
    }
}

template<int W>
__global__ void signpool_q(const int16_t* __restrict__ q, const float* __restrict__ bias,
                           const float2* __restrict__ bnp, const float* __restrict__ g,
                           const float* __restrict__ be, const int H, const int J,
                           uint64_t* __restrict__ aout)
{
    const int n  = blockIdx.y;
    const int j0 = blockIdx.x << 6;
    const int wave = threadIdx.x >> 6, lane = threadIdx.x & 63;
    const int nw = blockDim.x >> 6;
    const int C  = W * 64;
    const int jend = min(j0 + 64, J);
    for (int w = wave; w < W; w += nw) {
        const int c = (w << 6) + lane;
        const float2 mi = bnp[c];
        const float bb = bias[c], gg = g[c], bbe = be[c];
        for (int j = j0; j < jend; ++j) {
            float y0 = __fadd_rn(__fmul_rn(0.1f, (float)q[((size_t)n * H + 2 * j    ) * C + c]), bb);
            float y1v= __fadd_rn(__fmul_rn(0.1f, (float)q[((size_t)n * H + 2 * j + 1) * C + c]), bb);
            float t0 = __fadd_rn(__fmul_rn(__fmul_rn(__fsub_rn(y0,  mi.x), mi.y), gg), bbe);
            float t1 = __fadd_rn(__fmul_rn(__fmul_rn(__fsub_rn(y1v, mi.x), mi.y), gg), bbe);
            uint64_t word = __ballot((t0 >= 0.f) || (t1 >= 0.f));
            if (lane == 0) aout[((size_t)n * J + j) * W + w] = word;
        }
    }
}

// ------------------------------- FC ----------------------------------------
__global__ void fc_kernel(const uint64_t* __restrict__ a5, const uint64_t* __restrict__ wfcb,
                          float* __restrict__ out)
{
    const int n    = blockIdx.y;
    const int oc   = blockIdx.x * 4 + (threadIdx.x >> 6);
    const int lane = threadIdx.x & 63;
    if (oc >= 35) return;
    const uint64_t* arow = a5   + (size_t)n  * FCW;
    const uint64_t* wrow = wfcb + (size_t)oc * FCW;
    int X = 0;
    for (int i = lane; i < FCW; i += 64)
        X += __popcll(arow[i] ^ wrow[i]);
    for (int o = 32; o > 0; o >>= 1) X += __shfl_xor(X, o, 64);
    if (lane == 0) out[(size_t)n * 35 + oc] = 0.1f * (float)(127488 - 2 * X);
}

// ---------------------------------------------------------------------------
extern "C" void kernel_launch(void* const* d_in, const int* in_sizes, int n_in,
                              void* d_out, int out_size, void* d_ws, size_t ws_size,
                              hipStream_t stream)
{
    (void)in_sizes; (void)n_in; (void)out_size;
    const float* x   = (const float*)d_in[0];
    const float* w1  = (const float*)d_in[1];
    const float* b1  = (const float*)d_in[2];
    const float* g1  = (const float*)d_in[3];
    const float* be1 = (const float*)d_in[4];
    const float* w2  = (const float*)d_in[5];
    const float* b2  = (const float*)d_in[6];
    const float* g2  = (const float*)d_in[7];
    const float* be2 = (const float*)d_in[8];
    const float* w3  = (const float*)d_in[9];
    const float* b3  = (const float*)d_in[10];
    const float* g3  = (const float*)d_in[11];
    const float* be3 = (const float*)d_in[12];
    const float* w5  = (const float*)d_in[13];
    const float* b5  = (const float*)d_in[14];
    const float* g5  = (const float*)d_in[15];
    const float* be5 = (const float*)d_in[16];
    const float* wfc = (const float*)d_in[17];
    char* ws = (char*)d_ws;

    size_t cur = 0;
    auto take = [&](size_t bytes) {
        size_t r = cur;
        cur = (cur + bytes + 255) & ~(size_t)255;
        return r;
    };
    int16_t*  qb  = (int16_t*)(ws + take(33554432));   // stage q buffer (<=32.7 MB)
    int*      pq  = (int*)(ws + take(4194304));        // bconv stat partials
    uint64_t* a1  = (uint64_t*)(ws + take(2037760));
    uint64_t* a2  = (uint64_t*)(ws + take(1018880));
    uint64_t* a3  = (uint64_t*)(ws + take(1017856));
    uint64_t* a5  = (uint64_t*)(ws + take(1019904));
    uint64_t* wb2 = (uint64_t*)(ws + take(8192));
    uint64_t* wb3 = (uint64_t*)(ws + take(16384));
    uint64_t* wb5 = (uint64_t*)(ws + take(49152));
    uint64_t* wbf = (uint64_t*)(ws + take(557760));
    float*    w1p = (float*)(ws + take(43008));        // signed conv1 weights
    float*    p1  = (float*)(ws + take(524288));       // 1024 blocks x 128 floats
    float2*   bnp1 = (float2*)(ws + take(1024));
    float2*   bnp2 = (float2*)(ws + take(1024));
    float2*   bnp3 = (float2*)(ws + take(2048));
    float2*   bnp5 = (float2*)(ws + take(4096));
    if (cur > ws_size) return;   // insufficient workspace -> fail loudly

    hipLaunchKernelGGL(binarize_all, dim3(351), dim3(256), 0, stream,
                       w2, w3, w5, wfc, w1, wb2, wb3, wb5, wbf, w1p);
    // stage 1: stats pass, reduce, sign pass (no y1 materialization)
    hipLaunchKernelGGL(conv1_fused, dim3(8, 64, 2), dim3(256), 0, stream,
                       x, w1p, b1, (const float2*)nullptr, g1, be1, p1, a1, 0);
    hipLaunchKernelGGL(bn_reduce1, dim3(128), dim3(256), 0, stream, p1, bnp1);
    hipLaunchKernelGGL(conv1_fused, dim3(8, 64, 2), dim3(256), 0, stream,
                       x, w1p, b1, bnp1, g1, be1, p1, a1, 1);
    // stage 2
    hipLaunchKernelGGL((bconv<2, 4, 2, 128>), dim3(32, 64), dim3(128), 0, stream,
                       a1, wb2, J1, H2o, qb, pq);
    hipLaunchKernelGGL(bn_reduce_q, dim3(128), dim3(256), 0, stream,
                       pq, 2048, 128, (double)Bn * H2o, b2, bnp2);
    hipLaunchKernelGGL((signpool_q<2>), dim3(16, 64), dim3(128), 0, stream,
                       qb, b2, bnp2, g2, be2, H2o, J2, a2);
    // stage 3
    hipLaunchKernelGGL((bconv<2, 4, 1, 256>), dim3(16, 64), dim3(256), 0, stream,
                       a2, wb3, J2, H3o, qb, pq);
    hipLaunchKernelGGL(bn_reduce_q, dim3(256), dim3(256), 0, stream,
                       pq, 1024, 256, (double)Bn * H3o, b3, bnp3);
    hipLaunchKernelGGL((signpool_q<4>), dim3(8, 64), dim3(256), 0, stream,
                       qb, b3, bnp3, g3, be3, H3o, J3, a3);
    // stage 5
    hipLaunchKernelGGL((bconv<4, 3, 2, 512>), dim3(8, 64), dim3(512), 0, stream,
                       a3, wb5, J3, H5o, qb, pq);
    hipLaunchKernelGGL(bn_reduce_q, dim3(512), dim3(256), 0, stream,
                       pq, 512, 512, (double)Bn * H5o, b5, bnp5);
    hipLaunchKernelGGL((signpool_q<8>), dim3(4, 64), dim3(256), 0, stream,
                       qb, b5, bnp5, g5, be5, H5o, J5, a5);
    // FC
    hipLaunchKernelGGL(fc_kernel, dim3(9, 64), dim3(256), 0, stream,
                       a5, wbf, (float*)d_out);
}